// Round 3
// baseline (141.409 us; speedup 1.0000x reference)
//
#include <hip/hip_runtime.h>
#include <math.h>

#define N_NODES 50000
#define D_FEAT 96
#define N_EDGES 800000
#define NBLOCKS 2048

// 32 lanes cooperate on one edge. Lane j covers feature elems j, j+32, j+64:
// three coalesced 128B segments per gathered row.
// NOTE: harness delivers integer inputs as int32 (even though reference is int64).
__global__ __launch_bounds__(256) void edge_loss_kernel(
    const float* __restrict__ feat,
    const int* __restrict__ eidx,
    float* __restrict__ partial) {

    const int lane = threadIdx.x & 31;           // lane within 32-group
    const int gid  = (blockIdx.x * blockDim.x + threadIdx.x) >> 5;
    const int ngrp = (gridDim.x * blockDim.x) >> 5;

    float local = 0.0f;
    for (int e = gid; e < N_EDGES; e += ngrp) {
        const int s = eidx[e];
        const int d = eidx[N_EDGES + e];
        const float* __restrict__ fs = feat + (long long)s * D_FEAT;
        const float* __restrict__ fd = feat + (long long)d * D_FEAT;

        float acc = 0.0f;
#pragma unroll
        for (int k = 0; k < 3; ++k) {
            const float df = fs[lane + 32 * k] - fd[lane + 32 * k];
            acc += df * df;
        }
#pragma unroll
        for (int off = 16; off; off >>= 1)
            acc += __shfl_xor(acc, off, 32);

        if (lane == 0) local += sqrtf(acc);
    }

    // block-level reduction of the 8 per-group partials; plain store (no atomics)
    __shared__ float smem[8];
    const int grp_in_blk = threadIdx.x >> 5;
    if (lane == 0) smem[grp_in_blk] = local;
    __syncthreads();
    if (threadIdx.x == 0) {
        float bsum = 0.0f;
#pragma unroll
        for (int i = 0; i < 8; ++i) bsum += smem[i];
        partial[blockIdx.x] = bsum;   // every block writes its slot -> no init needed
    }
}

// Single block reduces NBLOCKS partials in double, writes mean.
__global__ __launch_bounds__(256) void finalize_kernel(
    const float* __restrict__ partial,
    float* __restrict__ out) {

    const int tid = threadIdx.x;
    double acc = 0.0;
#pragma unroll
    for (int i = 0; i < NBLOCKS / 256; ++i)
        acc += (double)partial[tid + 256 * i];

    // wave (64-lane) shuffle reduction
#pragma unroll
    for (int off = 32; off; off >>= 1)
        acc += __shfl_xor(acc, off, 64);

    __shared__ double smem[4];
    const int wave = tid >> 6;
    if ((tid & 63) == 0) smem[wave] = acc;
    __syncthreads();
    if (tid == 0) {
        double s = smem[0] + smem[1] + smem[2] + smem[3];
        out[0] = (float)(s / (double)N_EDGES);
    }
}

extern "C" void kernel_launch(void* const* d_in, const int* in_sizes, int n_in,
                              void* d_out, int out_size, void* d_ws, size_t ws_size,
                              hipStream_t stream) {
    const float* feat = (const float*)d_in[0];
    const int* eidx   = (const int*)d_in[1];   // int32 per harness convention
    float* out        = (float*)d_out;
    float* partial    = (float*)d_ws;

    edge_loss_kernel<<<NBLOCKS, 256, 0, stream>>>(feat, eidx, partial);
    finalize_kernel<<<1, 256, 0, stream>>>(partial, out);
}

// Round 4
// 110.853 us; speedup vs baseline: 1.2756x; 1.2756x over previous
//
#include <hip/hip_runtime.h>
#include <hip/hip_fp16.h>
#include <math.h>

#define N_NODES 50000
#define D_FEAT 96
#define N_EDGES 800000
#define NBLOCKS 2048

#define FEAT16_ELEMS (N_NODES * D_FEAT)               // 4.8M halfs = 9.6 MB
#define FEAT16_BYTES (FEAT16_ELEMS * 2)
#define PARTIAL_OFFSET ((FEAT16_BYTES + 63) & ~63)    // align partials
#define WS_NEEDED (PARTIAL_OFFSET + NBLOCKS * 4)

// ---------- fp16 path ----------

// Convert fp32 features -> fp16 table in workspace. float4 in, half4 (ushort4) out.
__global__ __launch_bounds__(256) void convert_kernel(
    const float* __restrict__ feat, __half* __restrict__ feat16) {

    const int tid = blockIdx.x * blockDim.x + threadIdx.x;
    const int nthr = gridDim.x * blockDim.x;
    const float4* __restrict__ in4 = (const float4*)feat;
    ushort4* __restrict__ out4 = (ushort4*)feat16;
    const int n4 = FEAT16_ELEMS / 4;   // 1.2M
    for (int i = tid; i < n4; i += nthr) {
        float4 v = in4[i];
        ushort4 o;
        o.x = __half_as_ushort(__float2half(v.x));
        o.y = __half_as_ushort(__float2half(v.y));
        o.z = __half_as_ushort(__float2half(v.z));
        o.w = __half_as_ushort(__float2half(v.w));
        out4[i] = o;
    }
}

// 16 lanes per edge; row = 48 half2 (192 B). Lane j reads half2 at j, j+16, j+32
// -> three 64 B coalesced segments per gathered row.
__global__ __launch_bounds__(256) void edge_loss_fp16_kernel(
    const __half* __restrict__ feat16,
    const int* __restrict__ eidx,
    float* __restrict__ partial) {

    const int lane = threadIdx.x & 15;
    const int gid  = (blockIdx.x * blockDim.x + threadIdx.x) >> 4;
    const int ngrp = (gridDim.x * blockDim.x) >> 4;
    const __half2* __restrict__ f2 = (const __half2*)feat16;

    float local = 0.0f;
    for (int e = gid; e < N_EDGES; e += ngrp) {
        const int s = eidx[e];
        const int d = eidx[N_EDGES + e];
        const __half2* __restrict__ fs = f2 + s * 48;
        const __half2* __restrict__ fd = f2 + d * 48;

        float acc = 0.0f;
#pragma unroll
        for (int k = 0; k < 3; ++k) {
            float2 a = __half22float2(fs[lane + 16 * k]);
            float2 b = __half22float2(fd[lane + 16 * k]);
            float dx = a.x - b.x, dy = a.y - b.y;
            acc += dx * dx + dy * dy;
        }
#pragma unroll
        for (int off = 8; off; off >>= 1)
            acc += __shfl_xor(acc, off, 16);

        if (lane == 0) local += sqrtf(acc);
    }

    __shared__ float smem[16];
    const int grp_in_blk = threadIdx.x >> 4;
    if (lane == 0) smem[grp_in_blk] = local;
    __syncthreads();
    if (threadIdx.x == 0) {
        float bsum = 0.0f;
#pragma unroll
        for (int i = 0; i < 16; ++i) bsum += smem[i];
        partial[blockIdx.x] = bsum;
    }
}

// ---------- fp32 fallback path (proven in R3) ----------

__global__ __launch_bounds__(256) void edge_loss_fp32_kernel(
    const float* __restrict__ feat,
    const int* __restrict__ eidx,
    float* __restrict__ partial) {

    const int lane = threadIdx.x & 31;
    const int gid  = (blockIdx.x * blockDim.x + threadIdx.x) >> 5;
    const int ngrp = (gridDim.x * blockDim.x) >> 5;

    float local = 0.0f;
    for (int e = gid; e < N_EDGES; e += ngrp) {
        const int s = eidx[e];
        const int d = eidx[N_EDGES + e];
        const float* __restrict__ fs = feat + s * D_FEAT;
        const float* __restrict__ fd = feat + d * D_FEAT;

        float acc = 0.0f;
#pragma unroll
        for (int k = 0; k < 3; ++k) {
            const float df = fs[lane + 32 * k] - fd[lane + 32 * k];
            acc += df * df;
        }
#pragma unroll
        for (int off = 16; off; off >>= 1)
            acc += __shfl_xor(acc, off, 32);

        if (lane == 0) local += sqrtf(acc);
    }

    __shared__ float smem[8];
    const int grp_in_blk = threadIdx.x >> 5;
    if (lane == 0) smem[grp_in_blk] = local;
    __syncthreads();
    if (threadIdx.x == 0) {
        float bsum = 0.0f;
#pragma unroll
        for (int i = 0; i < 8; ++i) bsum += smem[i];
        partial[blockIdx.x] = bsum;
    }
}

// ---------- finalize ----------

__global__ __launch_bounds__(256) void finalize_kernel(
    const float* __restrict__ partial,
    float* __restrict__ out) {

    const int tid = threadIdx.x;
    double acc = 0.0;
#pragma unroll
    for (int i = 0; i < NBLOCKS / 256; ++i)
        acc += (double)partial[tid + 256 * i];

#pragma unroll
    for (int off = 32; off; off >>= 1)
        acc += __shfl_xor(acc, off, 64);

    __shared__ double smem[4];
    const int wave = tid >> 6;
    if ((tid & 63) == 0) smem[wave] = acc;
    __syncthreads();
    if (tid == 0) {
        double s = smem[0] + smem[1] + smem[2] + smem[3];
        out[0] = (float)(s / (double)N_EDGES);
    }
}

extern "C" void kernel_launch(void* const* d_in, const int* in_sizes, int n_in,
                              void* d_out, int out_size, void* d_ws, size_t ws_size,
                              hipStream_t stream) {
    const float* feat = (const float*)d_in[0];
    const int* eidx   = (const int*)d_in[1];   // int32 per harness convention
    float* out        = (float*)d_out;

    if (ws_size >= (size_t)WS_NEEDED) {
        __half* feat16 = (__half*)d_ws;
        float* partial = (float*)((char*)d_ws + PARTIAL_OFFSET);
        convert_kernel<<<NBLOCKS, 256, 0, stream>>>(feat, feat16);
        edge_loss_fp16_kernel<<<NBLOCKS, 256, 0, stream>>>(feat16, eidx, partial);
        finalize_kernel<<<1, 256, 0, stream>>>(partial, out);
    } else {
        float* partial = (float*)d_ws;
        edge_loss_fp32_kernel<<<NBLOCKS, 256, 0, stream>>>(feat, eidx, partial);
        finalize_kernel<<<1, 256, 0, stream>>>(partial, out);
    }
}

// Round 5
// 91.578 us; speedup vs baseline: 1.5441x; 1.2105x over previous
//
#include <hip/hip_runtime.h>
#include <math.h>

#define N_NODES 50000
#define D_FEAT 96
#define N_EDGES 800000
#define NBLOCKS 2048

typedef float v2f __attribute__((ext_vector_type(2)));

#define FEAT8_BYTES (N_NODES * D_FEAT)                 // 4.8 MB fp8 table
#define PARTIAL_OFFSET ((FEAT8_BYTES + 255) & ~255)
#define WS_NEEDED (PARTIAL_OFFSET + NBLOCKS * 4)

// ---------- fp8 path ----------

// fp32 -> fp8 e4m3 (OCP, gfx950-native). Each thread: one float4 -> one dword.
__global__ __launch_bounds__(256) void convert_fp8_kernel(
    const float* __restrict__ feat, unsigned int* __restrict__ feat8) {

    const int tid  = blockIdx.x * blockDim.x + threadIdx.x;
    const int nthr = gridDim.x * blockDim.x;
    const float4* __restrict__ in4 = (const float4*)feat;
    const int n = (N_NODES * D_FEAT) / 4;   // 1.2M dwords out
    for (int i = tid; i < n; i += nthr) {
        float4 v = in4[i];
        int w = 0;
        w = __builtin_amdgcn_cvt_pk_fp8_f32(v.x, v.y, w, false);
        w = __builtin_amdgcn_cvt_pk_fp8_f32(v.z, v.w, w, true);
        feat8[i] = (unsigned int)w;
    }
}

// 8 lanes per edge; row = 24 dwords (96 B). Lane j reads dwords j, j+8, j+16
// -> three 32 B coalesced segments per gathered row.
__global__ __launch_bounds__(256) void edge_loss_fp8_kernel(
    const unsigned int* __restrict__ feat8,
    const int* __restrict__ eidx,
    float* __restrict__ partial) {

    const int lane = threadIdx.x & 7;
    const int gid  = (blockIdx.x * blockDim.x + threadIdx.x) >> 3;
    const int ngrp = (gridDim.x * blockDim.x) >> 3;

    float local = 0.0f;
    for (int e = gid; e < N_EDGES; e += ngrp) {
        const int s = eidx[e];
        const int d = eidx[N_EDGES + e];
        const unsigned int* __restrict__ fs = feat8 + s * 24;
        const unsigned int* __restrict__ fd = feat8 + d * 24;

        float acc = 0.0f;
#pragma unroll
        for (int k = 0; k < 3; ++k) {
            const int ws = (int)fs[lane + 8 * k];
            const int wd = (int)fd[lane + 8 * k];
            v2f s0 = __builtin_amdgcn_cvt_pk_f32_fp8(ws, false);
            v2f s1 = __builtin_amdgcn_cvt_pk_f32_fp8(ws, true);
            v2f d0 = __builtin_amdgcn_cvt_pk_f32_fp8(wd, false);
            v2f d1 = __builtin_amdgcn_cvt_pk_f32_fp8(wd, true);
            const float e0 = s0.x - d0.x;
            const float e1 = s0.y - d0.y;
            const float e2 = s1.x - d1.x;
            const float e3 = s1.y - d1.y;
            acc += e0 * e0 + e1 * e1 + e2 * e2 + e3 * e3;
        }
#pragma unroll
        for (int off = 4; off; off >>= 1)
            acc += __shfl_xor(acc, off, 8);

        if (lane == 0) local += sqrtf(acc);
    }

    __shared__ float smem[32];   // 32 edge-groups per 256-block
    if (lane == 0) smem[threadIdx.x >> 3] = local;
    __syncthreads();
    if (threadIdx.x == 0) {
        float bsum = 0.0f;
#pragma unroll
        for (int i = 0; i < 32; ++i) bsum += smem[i];
        partial[blockIdx.x] = bsum;
    }
}

// ---------- fp32 fallback path (proven in R3) ----------

__global__ __launch_bounds__(256) void edge_loss_fp32_kernel(
    const float* __restrict__ feat,
    const int* __restrict__ eidx,
    float* __restrict__ partial) {

    const int lane = threadIdx.x & 31;
    const int gid  = (blockIdx.x * blockDim.x + threadIdx.x) >> 5;
    const int ngrp = (gridDim.x * blockDim.x) >> 5;

    float local = 0.0f;
    for (int e = gid; e < N_EDGES; e += ngrp) {
        const int s = eidx[e];
        const int d = eidx[N_EDGES + e];
        const float* __restrict__ fs = feat + s * D_FEAT;
        const float* __restrict__ fd = feat + d * D_FEAT;

        float acc = 0.0f;
#pragma unroll
        for (int k = 0; k < 3; ++k) {
            const float df = fs[lane + 32 * k] - fd[lane + 32 * k];
            acc += df * df;
        }
#pragma unroll
        for (int off = 16; off; off >>= 1)
            acc += __shfl_xor(acc, off, 32);

        if (lane == 0) local += sqrtf(acc);
    }

    __shared__ float smem[8];
    const int grp_in_blk = threadIdx.x >> 5;
    if (lane == 0) smem[grp_in_blk] = local;
    __syncthreads();
    if (threadIdx.x == 0) {
        float bsum = 0.0f;
#pragma unroll
        for (int i = 0; i < 8; ++i) bsum += smem[i];
        partial[blockIdx.x] = bsum;
    }
}

// ---------- finalize ----------

__global__ __launch_bounds__(256) void finalize_kernel(
    const float* __restrict__ partial,
    float* __restrict__ out) {

    const int tid = threadIdx.x;
    double acc = 0.0;
#pragma unroll
    for (int i = 0; i < NBLOCKS / 256; ++i)
        acc += (double)partial[tid + 256 * i];

#pragma unroll
    for (int off = 32; off; off >>= 1)
        acc += __shfl_xor(acc, off, 64);

    __shared__ double smem[4];
    const int wave = tid >> 6;
    if ((tid & 63) == 0) smem[wave] = acc;
    __syncthreads();
    if (tid == 0) {
        double s = smem[0] + smem[1] + smem[2] + smem[3];
        out[0] = (float)(s / (double)N_EDGES);
    }
}

extern "C" void kernel_launch(void* const* d_in, const int* in_sizes, int n_in,
                              void* d_out, int out_size, void* d_ws, size_t ws_size,
                              hipStream_t stream) {
    const float* feat = (const float*)d_in[0];
    const int* eidx   = (const int*)d_in[1];   // int32 per harness convention
    float* out        = (float*)d_out;

    if (ws_size >= (size_t)WS_NEEDED) {
        unsigned int* feat8 = (unsigned int*)d_ws;
        float* partial = (float*)((char*)d_ws + PARTIAL_OFFSET);
        convert_fp8_kernel<<<NBLOCKS, 256, 0, stream>>>(feat, feat8);
        edge_loss_fp8_kernel<<<NBLOCKS, 256, 0, stream>>>(feat8, eidx, partial);
        finalize_kernel<<<1, 256, 0, stream>>>(partial, out);
    } else {
        float* partial = (float*)d_ws;
        edge_loss_fp32_kernel<<<NBLOCKS, 256, 0, stream>>>(feat, eidx, partial);
        finalize_kernel<<<1, 256, 0, stream>>>(partial, out);
    }
}

// Round 6
// 90.587 us; speedup vs baseline: 1.5610x; 1.0109x over previous
//
#include <hip/hip_runtime.h>
#include <math.h>

#define N_NODES 50000
#define D_FEAT 96
#define N_EDGES 800000
#define NBLOCKS 2048

typedef float v2f __attribute__((ext_vector_type(2)));

#define FEAT8_BYTES (N_NODES * D_FEAT)                 // 4.8 MB fp8 table
#define PARTIAL_OFFSET ((FEAT8_BYTES + 255) & ~255)
#define WS_NEEDED (PARTIAL_OFFSET + NBLOCKS * 4)

// 12-byte aligned-4 chunk: one lane's share of a 96 B row (8 lanes/row).
struct alignas(4) U3 { unsigned int x, y, z; };

// ---------- fp8 path ----------

// fp32 -> fp8 e4m3 (OCP, gfx950-native). Each thread: one float4 -> one dword.
__global__ __launch_bounds__(256) void convert_fp8_kernel(
    const float* __restrict__ feat, unsigned int* __restrict__ feat8) {

    const int tid  = blockIdx.x * blockDim.x + threadIdx.x;
    const int nthr = gridDim.x * blockDim.x;
    const float4* __restrict__ in4 = (const float4*)feat;
    const int n = (N_NODES * D_FEAT) / 4;   // 1.2M dwords out
    for (int i = tid; i < n; i += nthr) {
        float4 v = in4[i];
        int w = 0;
        w = __builtin_amdgcn_cvt_pk_fp8_f32(v.x, v.y, w, false);
        w = __builtin_amdgcn_cvt_pk_fp8_f32(v.z, v.w, w, true);
        feat8[i] = (unsigned int)w;
    }
}

// squared-diff accumulate for one dword (4 fp8 values each side)
__device__ __forceinline__ float acc_dw(unsigned int ws, unsigned int wd, float acc) {
    v2f s0 = __builtin_amdgcn_cvt_pk_f32_fp8((int)ws, false);
    v2f s1 = __builtin_amdgcn_cvt_pk_f32_fp8((int)ws, true);
    v2f d0 = __builtin_amdgcn_cvt_pk_f32_fp8((int)wd, false);
    v2f d1 = __builtin_amdgcn_cvt_pk_f32_fp8((int)wd, true);
    const float e0 = s0.x - d0.x;
    const float e1 = s0.y - d0.y;
    const float e2 = s1.x - d1.x;
    const float e3 = s1.y - d1.y;
    return acc + e0 * e0 + e1 * e1 + e2 * e2 + e3 * e3;
}

__device__ __forceinline__ U3 ld_row(const unsigned int* __restrict__ feat8,
                                     int node, int lane) {
    return *((const U3*)(feat8 + node * 24) + lane);   // 12 B contiguous per lane
}

// 8 lanes per edge; lane j loads bytes [12j, 12j+12) of each 96 B row
// -> ONE dwordx3 gather per row (vs 3 dword gathers before).
// Two edges per iteration for memory-level parallelism.
__global__ __launch_bounds__(256) void edge_loss_fp8_kernel(
    const unsigned int* __restrict__ feat8,
    const int* __restrict__ eidx,
    float* __restrict__ partial) {

    const int lane = threadIdx.x & 7;
    const int gid  = (blockIdx.x * blockDim.x + threadIdx.x) >> 3;
    const int ngrp = (gridDim.x * blockDim.x) >> 3;

    float local = 0.0f;
    int e = gid;
    for (; e + ngrp < N_EDGES; e += 2 * ngrp) {
        const int eB = e + ngrp;
        const int sA = eidx[e],  dA = eidx[N_EDGES + e];
        const int sB = eidx[eB], dB = eidx[N_EDGES + eB];
        // 4 independent dwordx3 gathers in flight
        const U3 a = ld_row(feat8, sA, lane);
        const U3 b = ld_row(feat8, dA, lane);
        const U3 c = ld_row(feat8, sB, lane);
        const U3 f = ld_row(feat8, dB, lane);

        float accA = 0.0f, accB = 0.0f;
        accA = acc_dw(a.x, b.x, accA);
        accA = acc_dw(a.y, b.y, accA);
        accA = acc_dw(a.z, b.z, accA);
        accB = acc_dw(c.x, f.x, accB);
        accB = acc_dw(c.y, f.y, accB);
        accB = acc_dw(c.z, f.z, accB);

#pragma unroll
        for (int off = 4; off; off >>= 1) {
            accA += __shfl_xor(accA, off, 8);
            accB += __shfl_xor(accB, off, 8);
        }
        if (lane == 0) local += sqrtf(accA) + sqrtf(accB);
    }
    if (e < N_EDGES) {
        const int s = eidx[e], d = eidx[N_EDGES + e];
        const U3 a = ld_row(feat8, s, lane);
        const U3 b = ld_row(feat8, d, lane);
        float acc = 0.0f;
        acc = acc_dw(a.x, b.x, acc);
        acc = acc_dw(a.y, b.y, acc);
        acc = acc_dw(a.z, b.z, acc);
#pragma unroll
        for (int off = 4; off; off >>= 1)
            acc += __shfl_xor(acc, off, 8);
        if (lane == 0) local += sqrtf(acc);
    }

    __shared__ float smem[32];   // 32 edge-groups per 256-block
    if (lane == 0) smem[threadIdx.x >> 3] = local;
    __syncthreads();
    if (threadIdx.x == 0) {
        float bsum = 0.0f;
#pragma unroll
        for (int i = 0; i < 32; ++i) bsum += smem[i];
        partial[blockIdx.x] = bsum;
    }
}

// ---------- fp32 fallback path (proven in R3) ----------

__global__ __launch_bounds__(256) void edge_loss_fp32_kernel(
    const float* __restrict__ feat,
    const int* __restrict__ eidx,
    float* __restrict__ partial) {

    const int lane = threadIdx.x & 31;
    const int gid  = (blockIdx.x * blockDim.x + threadIdx.x) >> 5;
    const int ngrp = (gridDim.x * blockDim.x) >> 5;

    float local = 0.0f;
    for (int e = gid; e < N_EDGES; e += ngrp) {
        const int s = eidx[e];
        const int d = eidx[N_EDGES + e];
        const float* __restrict__ fs = feat + s * D_FEAT;
        const float* __restrict__ fd = feat + d * D_FEAT;

        float acc = 0.0f;
#pragma unroll
        for (int k = 0; k < 3; ++k) {
            const float df = fs[lane + 32 * k] - fd[lane + 32 * k];
            acc += df * df;
        }
#pragma unroll
        for (int off = 16; off; off >>= 1)
            acc += __shfl_xor(acc, off, 32);

        if (lane == 0) local += sqrtf(acc);
    }

    __shared__ float smem[8];
    const int grp_in_blk = threadIdx.x >> 5;
    if (lane == 0) smem[grp_in_blk] = local;
    __syncthreads();
    if (threadIdx.x == 0) {
        float bsum = 0.0f;
#pragma unroll
        for (int i = 0; i < 8; ++i) bsum += smem[i];
        partial[blockIdx.x] = bsum;
    }
}

// ---------- finalize ----------

__global__ __launch_bounds__(256) void finalize_kernel(
    const float* __restrict__ partial,
    float* __restrict__ out) {

    const int tid = threadIdx.x;
    double acc = 0.0;
#pragma unroll
    for (int i = 0; i < NBLOCKS / 256; ++i)
        acc += (double)partial[tid + 256 * i];

#pragma unroll
    for (int off = 32; off; off >>= 1)
        acc += __shfl_xor(acc, off, 64);

    __shared__ double smem[4];
    const int wave = tid >> 6;
    if ((tid & 63) == 0) smem[wave] = acc;
    __syncthreads();
    if (tid == 0) {
        double s = smem[0] + smem[1] + smem[2] + smem[3];
        out[0] = (float)(s / (double)N_EDGES);
    }
}

extern "C" void kernel_launch(void* const* d_in, const int* in_sizes, int n_in,
                              void* d_out, int out_size, void* d_ws, size_t ws_size,
                              hipStream_t stream) {
    const float* feat = (const float*)d_in[0];
    const int* eidx   = (const int*)d_in[1];   // int32 per harness convention
    float* out        = (float*)d_out;

    if (ws_size >= (size_t)WS_NEEDED) {
        unsigned int* feat8 = (unsigned int*)d_ws;
        float* partial = (float*)((char*)d_ws + PARTIAL_OFFSET);
        convert_fp8_kernel<<<NBLOCKS, 256, 0, stream>>>(feat, feat8);
        edge_loss_fp8_kernel<<<NBLOCKS, 256, 0, stream>>>(feat8, eidx, partial);
        finalize_kernel<<<1, 256, 0, stream>>>(partial, out);
    } else {
        float* partial = (float*)d_ws;
        edge_loss_fp32_kernel<<<NBLOCKS, 256, 0, stream>>>(feat, eidx, partial);
        finalize_kernel<<<1, 256, 0, stream>>>(partial, out);
    }
}